// Round 9
// baseline (148.162 us; speedup 1.0000x reference)
//
#include <hip/hip_runtime.h>

// Geometry: G=256 graphs x 64 nodes, H=8 heads x D=8, IN_DIM=EDGE_DIM=64
// EF = 1048576 full edges, ES = 262144 sparse edges.
// edge f = b*4096 + i*64 + j (src=i, dst=j); sparse s = b*1024 + j*16 + k, i=(j+1+k)&63.
//
// Staging: d_out eout region: Qs @0, Ks @1048576, Vs @2097152, PEs @3145728.
//          d_ws: scsp [262144*8] @0, M2 [576] @2097152.
// NOTE launch_bounds: (X, >=4) caps VGPR at 64 and SPILLS if demand>64 (r2/r3).
// NOTE code size: ~50KB monolith bodies are frontend-bound (r1-r4); small GEMM
// loops with SGPR-streamed weights MUST stay fully unrolled (r5: eout 26->93us).
// NOTE attn is TLP+MLP-latency-bound: keep LDS <= 48KB (r7), and HOIST read-once
// global loads (rel/adj) into registers with static indices BEFORE the barrier --
// in-loop loads keep only ~1 iter of MLP in flight (r6/r8: 750 GB/s on rel).
// NOTE lgkmcnt is shared by DS and SMEM: hoist LDS reads out of s_load/FMA
// streams (r8 eout: JIT ds_reads -> 31% VALU duty).

// qkv half (blocks 0..255) + pe half (blocks 256..767), independent.
__global__ __launch_bounds__(512, 2) void qkvpe_kernel(
    const float* __restrict__ h,
    const float* __restrict__ e,
    const float* __restrict__ Wq, const float* __restrict__ bq,
    const float* __restrict__ Wk, const float* __restrict__ bk,
    const float* __restrict__ Wv, const float* __restrict__ bv,
    const float* __restrict__ Wpe, const float* __restrict__ bpe,
    float* __restrict__ Qs, float* __restrict__ Ks, float* __restrict__ Vs,
    float* __restrict__ PEs)
{
    const int t = threadIdx.x;
    if (blockIdx.x < 256) {
        const int b    = blockIdx.x;
        const int lane = t & 63;
        const int wu   = __builtin_amdgcn_readfirstlane(t >> 6);   // 8 cols per wave
        const float* hrow = h + (size_t)(b * 64 + lane) * 64;
        float accQ[8], accK[8], accV[8];
        #pragma unroll
        for (int cc = 0; cc < 8; ++cc) {
            const int c = wu * 8 + cc;
            accQ[cc] = bq[c]; accK[cc] = bk[c]; accV[cc] = bv[c];
        }
        #pragma unroll 1
        for (int k0 = 0; k0 < 4; ++k0) {
            float hv[16];
            #pragma unroll
            for (int u = 0; u < 4; ++u) {
                const float4 x = ((const float4*)hrow)[k0 * 4 + u];
                hv[u*4+0] = x.x; hv[u*4+1] = x.y; hv[u*4+2] = x.z; hv[u*4+3] = x.w;
            }
            #pragma unroll
            for (int cc = 0; cc < 8; ++cc) {
                const int c = wu * 8 + cc;
                const float* wq  = Wq + c * 64 + k0 * 16;   // wave-uniform -> s_load
                const float* wk  = Wk + c * 64 + k0 * 16;
                const float* wvp = Wv + c * 64 + k0 * 16;
                #pragma unroll
                for (int k = 0; k < 16; ++k) {
                    accQ[cc] = fmaf(hv[k], wq[k],  accQ[cc]);
                    accK[cc] = fmaf(hv[k], wk[k],  accK[cc]);
                    accV[cc] = fmaf(hv[k], wvp[k], accV[cc]);
                }
            }
        }
        const size_t o = (size_t)(b * 64 + lane) * 64 + wu * 8;
        *(float4*)(Qs + o)     = make_float4(accQ[0], accQ[1], accQ[2], accQ[3]);
        *(float4*)(Qs + o + 4) = make_float4(accQ[4], accQ[5], accQ[6], accQ[7]);
        *(float4*)(Ks + o)     = make_float4(accK[0], accK[1], accK[2], accK[3]);
        *(float4*)(Ks + o + 4) = make_float4(accK[4], accK[5], accK[6], accK[7]);
        *(float4*)(Vs + o)     = make_float4(accV[0], accV[1], accV[2], accV[3]);
        *(float4*)(Vs + o + 4) = make_float4(accV[4], accV[5], accV[6], accV[7]);
    } else {
        const int row = (blockIdx.x - 256) * 512 + t;      // 0..ES-1
        const float* erow = e + (size_t)row * 64;
        float acc[8];
        #pragma unroll
        for (int h2 = 0; h2 < 8; ++h2) acc[h2] = bpe[h2];
        #pragma unroll 1
        for (int k0 = 0; k0 < 4; ++k0) {
            float ev[16];
            #pragma unroll
            for (int u = 0; u < 4; ++u) {
                const float4 x = ((const float4*)erow)[k0 * 4 + u];
                ev[u*4+0] = x.x; ev[u*4+1] = x.y; ev[u*4+2] = x.z; ev[u*4+3] = x.w;
            }
            #pragma unroll
            for (int h2 = 0; h2 < 8; ++h2) {
                const float* wp = Wpe + h2 * 64 + k0 * 16;  // uniform -> s_load
                #pragma unroll
                for (int k = 0; k < 16; ++k)
                    acc[h2] = fmaf(ev[k], wp[k], acc[h2]);
            }
        }
        float* p0 = PEs + (size_t)row * 8;
        *(float4*)(p0)     = make_float4(acc[0], acc[1], acc[2], acc[3]);
        *(float4*)(p0 + 4) = make_float4(acc[4], acc[5], acc[6], acc[7]);
    }
}

// Core: K/V/PE in LDS (48KB -> grid-limited 2 blocks/CU). adj/rel register-
// prefetched (64 loads in flight/wave). PE cells become SC in-place; wV into
// dead shK; SC dumped coalesced.
__global__ __launch_bounds__(512, 2) void attn_kernel(
    const float* __restrict__ Qs, const float* __restrict__ Ks,
    const float* __restrict__ Vs, const float* __restrict__ PEs,
    const float* __restrict__ adj2,
    const float* __restrict__ rel,
    const float* __restrict__ Wo, const float* __restrict__ bo,
    float* __restrict__ h_out,
    float* __restrict__ scsp)
{
    __shared__ float shK[64 * 64];   // swizzled: row r, colgrp g at r*64 + ((g^(r&7))<<3)
    __shared__ float shV[64 * 64];   // (shK reused as wV[32][64] after the loop)
    __shared__ float shPE[512 * 8];  // proj_e -> overwritten in-place with sc_sp

    const int b2   = blockIdx.x;
    const int b    = b2 >> 1;
    const int joff = (b2 & 1) << 5;          // 0 or 32
    const int t    = threadIdx.x;

    const int j_local = t >> 4;
    const int hh      = (t >> 1) & 7;
    const int half    = t & 1;
    const int j       = joff + j_local;

    // ---- register prefetch: all 32 adj + 32 rel for this thread (read-once data).
    // Issued first; the staging barrier's vmcnt drain is where they land.
    const float* adjB = adj2 + (size_t)b * 4096 + j;
    const float* relB = rel  + ((size_t)b * 4096 + j) * 8 + hh;
    float A[32], R[32];
    #pragma unroll
    for (int it = 0; it < 32; ++it) {
        const int i = (half << 5) + it;
        A[it] = adjB[(size_t)i * 64];
        R[it] = relB[(size_t)i * 512];
    }

    // ---- stage K, V, PE (coalesced), Q per-thread
    {
        const int r = t >> 3, g = t & 7;
        const int d = r * 64 + ((g ^ (r & 7)) << 3);
        const float* kp = Ks + (size_t)b * 4096 + t * 8;
        const float* vp = Vs + (size_t)b * 4096 + t * 8;
        *(float4*)&shK[d]     = *(const float4*)(kp);
        *(float4*)&shK[d + 4] = *(const float4*)(kp + 4);
        *(float4*)&shV[d]     = *(const float4*)(vp);
        *(float4*)&shV[d + 4] = *(const float4*)(vp + 4);
        const float* pp = PEs + ((size_t)b * 1024 + joff * 16 + t) * 8;
        *(float4*)&shPE[t * 8]     = *(const float4*)(pp);
        *(float4*)&shPE[t * 8 + 4] = *(const float4*)(pp + 4);
    }
    float q[8];
    {
        const float* qp = Qs + (size_t)(b * 64 + j) * 64 + hh * 8;
        const float4 a = *(const float4*)qp;
        const float4 c = *(const float4*)(qp + 4);
        q[0]=a.x; q[1]=a.y; q[2]=a.z; q[3]=a.w;
        q[4]=c.x; q[5]=c.y; q[6]=c.z; q[7]=c.w;
    }
    __syncthreads();

    // ---- P3: scores + online softmax; loop is pure LDS/VALU (no VMEM)
    float den = 0.f;
    float wv[8] = {0.f,0.f,0.f,0.f,0.f,0.f,0.f,0.f};
    const float inv_scale = 0.35355339059327379f;  // 1/sqrt(8)
    #pragma unroll 4
    for (int it = 0; it < 32; ++it) {
        const int i  = (half << 5) + it;
        const int kb = i * 64 + ((hh ^ (i & 7)) << 3);
        const float4 kA = *(const float4*)&shK[kb];
        const float4 kB = *(const float4*)&shK[kb + 4];
        float s;
        s = kA.x * q[0];
        s = fmaf(kA.y, q[1], s); s = fmaf(kA.z, q[2], s); s = fmaf(kA.w, q[3], s);
        s = fmaf(kB.x, q[4], s); s = fmaf(kB.y, q[5], s); s = fmaf(kB.z, q[6], s);
        s = fmaf(kB.w, q[7], s);
        s = fmaf(s * inv_scale, A[it], R[it]);    // raw score (pre proj_e, unclipped)
        const int kidx = (i - j - 1) & 63;
        if (kidx < 16) {                          // sparse edge (i -> j)
            const int x = (j_local * 16 + kidx) * 8 + hh;
            const float pe = shPE[x];             // read proj_e (once, owner thread)
            shPE[x] = s;                          // overwrite with sc_sp (in-place)
            s += pe;                              // softmax sees sc_sp + proj_e
        }
        s = fminf(fmaxf(s, -5.f), 5.f);
        const float ex = __expf(s);
        den += ex;
        const float4 vA = *(const float4*)&shV[kb];
        const float4 vB = *(const float4*)&shV[kb + 4];
        wv[0] = fmaf(ex, vA.x, wv[0]); wv[1] = fmaf(ex, vA.y, wv[1]);
        wv[2] = fmaf(ex, vA.z, wv[2]); wv[3] = fmaf(ex, vA.w, wv[3]);
        wv[4] = fmaf(ex, vB.x, wv[4]); wv[5] = fmaf(ex, vB.y, wv[5]);
        wv[6] = fmaf(ex, vB.z, wv[6]); wv[7] = fmaf(ex, vB.w, wv[7]);
    }
    den += __shfl_xor(den, 1);
    #pragma unroll
    for (int u = 0; u < 8; ++u) wv[u] += __shfl_xor(wv[u], 1);
    __syncthreads();                 // all K/V reads + PE->SC swaps complete

    // ---- P4: coalesced sc_sp dump (thread t -> sparse row t); wV -> dead shK
    {
        const float4 a = *(const float4*)&shPE[t * 8];
        const float4 c = *(const float4*)&shPE[t * 8 + 4];
        float* sp = scsp + (size_t)((size_t)b * 1024 + joff * 16 + t) * 8;
        *(float4*)(sp)     = a;
        *(float4*)(sp + 4) = c;
    }
    if (half == 0) {
        const float id = 1.f / den;
        float* wp = &shK[j_local * 64 + hh * 8];   // shK := wV[32][64], plain layout
        *(float4*)(wp)     = make_float4(wv[0]*id, wv[1]*id, wv[2]*id, wv[3]*id);
        *(float4*)(wp + 4) = make_float4(wv[4]*id, wv[5]*id, wv[6]*id, wv[7]*id);
    }
    __syncthreads();

    // ---- P5: h_out = wV @ Wo^T + bo. thread = (rl = t>>4, cq = t&15)
    {
        const int rl = t >> 4;
        const int cq = t & 15;
        float acc[4];
        #pragma unroll
        for (int u = 0; u < 4; ++u) acc[u] = bo[cq * 4 + u];
        // hoist the full wV row chunk reads, then pure FMA/s_load
        float tv[64];
        #pragma unroll
        for (int v = 0; v < 16; ++v) {
            const float4 x = *(const float4*)&shK[rl * 64 + v * 4];
            tv[v*4+0] = x.x; tv[v*4+1] = x.y; tv[v*4+2] = x.z; tv[v*4+3] = x.w;
        }
        #pragma unroll
        for (int u = 0; u < 4; ++u) {
            const float* wo = Wo + (cq * 4 + u) * 64;   // uniform -> s_load stream
            #pragma unroll
            for (int k = 0; k < 64; ++k)
                acc[u] = fmaf(tv[k], wo[k], acc[u]);
        }
        float* orow = h_out + (size_t)(b * 64 + joff + rl) * 64 + cq * 4;
        *(float4*)orow = make_float4(acc[0], acc[1], acc[2], acc[3]);
    }
}

// Fold: e_out = e @ Woe^T + sc_sp @ M2^T + bc,  M2 = Woe@Wap [64x8],
// bc[c] = boe[c] + sum_k bap[k]*Woe[c,k].
__global__ void prep_kernel(const float* __restrict__ Wap, const float* __restrict__ bap,
                            const float* __restrict__ Woe, const float* __restrict__ boe,
                            float* __restrict__ M2)
{
    const int t = blockIdx.x * 64 + threadIdx.x;   // 576 threads total
    if (t < 512) {
        const int c = t >> 3, hq = t & 7;
        float s = 0.f;
        #pragma unroll 8
        for (int k = 0; k < 64; ++k) s = fmaf(Woe[c * 64 + k], Wap[k * 8 + hq], s);
        M2[t] = s;
    } else if (t < 576) {
        const int c = t - 512;
        float s = boe[c];
        #pragma unroll 8
        for (int k = 0; k < 64; ++k) s = fmaf(bap[k], Woe[t * 64 + k], s);
        M2[512 + c] = s;
    }
}

// eout: LDS-tiled, 64 rows/block, wave = 16-col group, lane = row. Full row
// hoisted to registers (one b128 burst) -> pure u-major FMA + s_load stream.
__global__ __launch_bounds__(256, 2) void eout_kernel(
    const float* __restrict__ e,
    const float* __restrict__ scsp,
    const float* __restrict__ Woe,
    const float* __restrict__ M2g,     // [512] M2 then [64] bc
    float* __restrict__ e_out)
{
    __shared__ float shE[64 * 64];   // swizzled: chunk cc of row r at r*64 + ((cc^(r&15))<<2)
    __shared__ float shS[64 * 8];

    const int t    = threadIdx.x;
    const int base = blockIdx.x * 64;

    {   // coop e-tile load: thread = (r = t>>2, qq = t&3), 4 float4
        const int r = t >> 2, qq = t & 3;
        const float* ep = e + (size_t)(base + r) * 64 + qq * 16;
        #pragma unroll
        for (int u = 0; u < 4; ++u) {
            const float4 x = ((const float4*)ep)[u];
            const int cc = qq * 4 + u;
            *(float4*)&shE[r * 64 + ((cc ^ (r & 15)) << 2)] = x;
        }
    }
    if (t < 128) {
        const int r = t >> 1, pp = t & 1;
        *(float4*)&shS[r * 8 + pp * 4] =
            *(const float4*)(scsp + (size_t)(base + r) * 8 + pp * 4);
    }
    __syncthreads();

    const int w = __builtin_amdgcn_readfirstlane(t >> 6);  // col group, uniform
    const int r = t & 63;

    // hoist full row + sc into registers: one LDS burst, then zero DS in FMA stream
    float ev[64];
    #pragma unroll
    for (int v = 0; v < 16; ++v) {
        const float4 x = *(const float4*)&shE[r * 64 + ((v ^ (r & 15)) << 2)];
        ev[v*4+0] = x.x; ev[v*4+1] = x.y; ev[v*4+2] = x.z; ev[v*4+3] = x.w;
    }
    float sc[8];
    {
        const float4 a  = *(const float4*)&shS[r * 8];
        const float4 c4 = *(const float4*)&shS[r * 8 + 4];
        sc[0]=a.x; sc[1]=a.y; sc[2]=a.z; sc[3]=a.w;
        sc[4]=c4.x; sc[5]=c4.y; sc[6]=c4.z; sc[7]=c4.w;
    }
    float acc[16];
    #pragma unroll
    for (int u = 0; u < 16; ++u) {
        const int c = w * 16 + u;                       // wave-uniform
        float s = M2g[512 + c];
        #pragma unroll
        for (int hq = 0; hq < 8; ++hq)
            s = fmaf(sc[hq], M2g[c * 8 + hq], s);
        acc[u] = s;
    }
    #pragma unroll
    for (int u = 0; u < 16; ++u) {
        const float* wr = Woe + (w * 16 + u) * 64;      // uniform -> s_load stream
        #pragma unroll
        for (int k = 0; k < 64; ++k)
            acc[u] = fmaf(ev[k], wr[k], acc[u]);
    }
    float* orow = e_out + (size_t)(base + r) * 64 + w * 16;
    #pragma unroll
    for (int u = 0; u < 4; ++u)
        *(float4*)&orow[u * 4] =
            make_float4(acc[u*4+0], acc[u*4+1], acc[u*4+2], acc[u*4+3]);
}

extern "C" void kernel_launch(void* const* d_in, const int* in_sizes, int n_in,
                              void* d_out, int out_size, void* d_ws, size_t ws_size,
                              hipStream_t stream) {
    const float* h    = (const float*)d_in[0];
    const float* e    = (const float*)d_in[1];
    const float* adj2 = (const float*)d_in[2];
    const float* rel  = (const float*)d_in[3];
    const float* Wq   = (const float*)d_in[4];  const float* bq  = (const float*)d_in[5];
    const float* Wk   = (const float*)d_in[6];  const float* bk  = (const float*)d_in[7];
    const float* Wv   = (const float*)d_in[8];  const float* bv  = (const float*)d_in[9];
    const float* Wpe  = (const float*)d_in[10]; const float* bpe = (const float*)d_in[11];
    const float* Wap  = (const float*)d_in[12]; const float* bap = (const float*)d_in[13];
    const float* Wo   = (const float*)d_in[14]; const float* bo  = (const float*)d_in[15];
    const float* Woe  = (const float*)d_in[16]; const float* boe = (const float*)d_in[17];

    float* out  = (float*)d_out;
    float* hout = out;                        // [16384*64]
    float* eout = out + 16384 * 64;           // [262144*64], staging (dead at eout time)
    float* Qs   = eout;                       // 1048576 floats
    float* Ks   = eout + 1048576;
    float* Vs   = eout + 2097152;
    float* PEs  = eout + 3145728;             // 2097152 floats
    float* ws   = (float*)d_ws;
    float* scsp = ws;                         // [262144*8]
    float* M2g  = ws + 2097152;               // [576]

    prep_kernel<<<dim3(9), dim3(64), 0, stream>>>(Wap, bap, Woe, boe, M2g);
    qkvpe_kernel<<<dim3(768), dim3(512), 0, stream>>>(
        h, e, Wq, bq, Wk, bk, Wv, bv, Wpe, bpe, Qs, Ks, Vs, PEs);
    attn_kernel<<<dim3(512), dim3(512), 0, stream>>>(
        Qs, Ks, Vs, PEs, adj2, rel, Wo, bo, hout, scsp);
    eout_kernel<<<dim3(4096), dim3(256), 0, stream>>>(e, scsp, Woe, M2g, eout);
}

// Round 10
// 145.326 us; speedup vs baseline: 1.0195x; 1.0195x over previous
//
#include <hip/hip_runtime.h>

// Geometry: G=256 graphs x 64 nodes, H=8 heads x D=8, IN_DIM=EDGE_DIM=64
// EF = 1048576 full edges, ES = 262144 sparse edges.
// edge f = b*4096 + i*64 + j (src=i, dst=j); sparse s = b*1024 + j*16 + k, i=(j+1+k)&63.
//
// Staging: d_out eout region: Qs @0, Ks @1048576, Vs @2097152, PEs @3145728.
//          d_ws: scsp [262144*8] @0, M2 [576] @2097152.
// NOTE launch_bounds: (X, >=4) caps VGPR at 64 and SPILLS if demand>64 (r2/r3).
// NOTE code size: ~50KB monolith bodies are frontend-bound (r1-r4); small GEMM
// loops with SGPR-streamed weights MUST stay fully unrolled (r5: eout 26->93us).
// NOTE attn is LATENCY-bound (r6-r9: 60-66us across all scheduling variants,
// VALU<16%, HBM<10%): the levers are waves/CU and serial-chain length, NOT
// instruction scheduling. r9's register prefetch (VGPR 92) hurt. Keep VGPR<64.

// qkv half (blocks 0..255) + pe half (blocks 256..767), independent.
__global__ __launch_bounds__(512, 2) void qkvpe_kernel(
    const float* __restrict__ h,
    const float* __restrict__ e,
    const float* __restrict__ Wq, const float* __restrict__ bq,
    const float* __restrict__ Wk, const float* __restrict__ bk,
    const float* __restrict__ Wv, const float* __restrict__ bv,
    const float* __restrict__ Wpe, const float* __restrict__ bpe,
    float* __restrict__ Qs, float* __restrict__ Ks, float* __restrict__ Vs,
    float* __restrict__ PEs)
{
    const int t = threadIdx.x;
    if (blockIdx.x < 256) {
        const int b    = blockIdx.x;
        const int lane = t & 63;
        const int wu   = __builtin_amdgcn_readfirstlane(t >> 6);   // 8 cols per wave
        const float* hrow = h + (size_t)(b * 64 + lane) * 64;
        float accQ[8], accK[8], accV[8];
        #pragma unroll
        for (int cc = 0; cc < 8; ++cc) {
            const int c = wu * 8 + cc;
            accQ[cc] = bq[c]; accK[cc] = bk[c]; accV[cc] = bv[c];
        }
        #pragma unroll 1
        for (int k0 = 0; k0 < 4; ++k0) {
            float hv[16];
            #pragma unroll
            for (int u = 0; u < 4; ++u) {
                const float4 x = ((const float4*)hrow)[k0 * 4 + u];
                hv[u*4+0] = x.x; hv[u*4+1] = x.y; hv[u*4+2] = x.z; hv[u*4+3] = x.w;
            }
            #pragma unroll
            for (int cc = 0; cc < 8; ++cc) {
                const int c = wu * 8 + cc;
                const float* wq  = Wq + c * 64 + k0 * 16;   // wave-uniform -> s_load
                const float* wk  = Wk + c * 64 + k0 * 16;
                const float* wvp = Wv + c * 64 + k0 * 16;
                #pragma unroll
                for (int k = 0; k < 16; ++k) {
                    accQ[cc] = fmaf(hv[k], wq[k],  accQ[cc]);
                    accK[cc] = fmaf(hv[k], wk[k],  accK[cc]);
                    accV[cc] = fmaf(hv[k], wvp[k], accV[cc]);
                }
            }
        }
        const size_t o = (size_t)(b * 64 + lane) * 64 + wu * 8;
        *(float4*)(Qs + o)     = make_float4(accQ[0], accQ[1], accQ[2], accQ[3]);
        *(float4*)(Qs + o + 4) = make_float4(accQ[4], accQ[5], accQ[6], accQ[7]);
        *(float4*)(Ks + o)     = make_float4(accK[0], accK[1], accK[2], accK[3]);
        *(float4*)(Ks + o + 4) = make_float4(accK[4], accK[5], accK[6], accK[7]);
        *(float4*)(Vs + o)     = make_float4(accV[0], accV[1], accV[2], accV[3]);
        *(float4*)(Vs + o + 4) = make_float4(accV[4], accV[5], accV[6], accV[7]);
    } else {
        const int row = (blockIdx.x - 256) * 512 + t;      // 0..ES-1
        const float* erow = e + (size_t)row * 64;
        float acc[8];
        #pragma unroll
        for (int h2 = 0; h2 < 8; ++h2) acc[h2] = bpe[h2];
        #pragma unroll 1
        for (int k0 = 0; k0 < 4; ++k0) {
            float ev[16];
            #pragma unroll
            for (int u = 0; u < 4; ++u) {
                const float4 x = ((const float4*)erow)[k0 * 4 + u];
                ev[u*4+0] = x.x; ev[u*4+1] = x.y; ev[u*4+2] = x.z; ev[u*4+3] = x.w;
            }
            #pragma unroll
            for (int h2 = 0; h2 < 8; ++h2) {
                const float* wp = Wpe + h2 * 64 + k0 * 16;  // uniform -> s_load
                #pragma unroll
                for (int k = 0; k < 16; ++k)
                    acc[h2] = fmaf(ev[k], wp[k], acc[h2]);
            }
        }
        float* p0 = PEs + (size_t)row * 8;
        *(float4*)(p0)     = make_float4(acc[0], acc[1], acc[2], acc[3]);
        *(float4*)(p0 + 4) = make_float4(acc[4], acc[5], acc[6], acc[7]);
    }
}

// Core: 1024 threads = (j_local 0..31, hh 0..7, quarter 0..3), 16 i's/thread.
// K/V/PE in 48KB LDS (2 blocks/CU = 32 waves/CU if VGPR<=64). In-loop adj/rel
// loads; PE cells -> SC in-place; wV into dead shK; SC dumped coalesced.
__global__ __launch_bounds__(1024, 2) void attn_kernel(
    const float* __restrict__ Qs, const float* __restrict__ Ks,
    const float* __restrict__ Vs, const float* __restrict__ PEs,
    const float* __restrict__ adj2,
    const float* __restrict__ rel,
    const float* __restrict__ Wo, const float* __restrict__ bo,
    float* __restrict__ h_out,
    float* __restrict__ scsp)
{
    __shared__ float shK[64 * 64];   // swizzled: row r, colgrp g at r*64 + ((g^(r&7))<<3)
    __shared__ float shV[64 * 64];   // (shK reused as wV[32][64] after the loop)
    __shared__ float shPE[512 * 8];  // proj_e -> overwritten in-place with sc_sp

    const int b2   = blockIdx.x;
    const int b    = b2 >> 1;
    const int joff = (b2 & 1) << 5;          // 0 or 32
    const int t    = threadIdx.x;

    const int j_local = t >> 5;              // 0..31
    const int hh      = (t >> 2) & 7;        // 0..7
    const int q4      = t & 3;               // 0..3 (i-quarter)
    const int j       = joff + j_local;

    // ---- stage K, V (swizzled), PE (plain), one float4 per thread; Q per-thread
    {
        const int r  = t >> 4;               // 0..63
        const int gh = t & 15;               // half-group 0..15
        const int g  = gh >> 1, lo = (gh & 1) * 4;
        const int d  = r * 64 + ((g ^ (r & 7)) << 3) + lo;
        const int so = r * 64 + g * 8 + lo;
        shK[d + 0] = Ks[(size_t)b * 4096 + so + 0];
        shK[d + 1] = Ks[(size_t)b * 4096 + so + 1];
        shK[d + 2] = Ks[(size_t)b * 4096 + so + 2];
        shK[d + 3] = Ks[(size_t)b * 4096 + so + 3];
        shV[d + 0] = Vs[(size_t)b * 4096 + so + 0];
        shV[d + 1] = Vs[(size_t)b * 4096 + so + 1];
        shV[d + 2] = Vs[(size_t)b * 4096 + so + 2];
        shV[d + 3] = Vs[(size_t)b * 4096 + so + 3];
        *(float4*)&shPE[t * 4] =
            *(const float4*)(PEs + ((size_t)b * 1024 + joff * 16) * 8 + t * 4);
    }
    float q[8];
    {
        const float* qp = Qs + (size_t)(b * 64 + j) * 64 + hh * 8;
        const float4 a = *(const float4*)qp;
        const float4 c = *(const float4*)(qp + 4);
        q[0]=a.x; q[1]=a.y; q[2]=a.z; q[3]=a.w;
        q[4]=c.x; q[5]=c.y; q[6]=c.z; q[7]=c.w;
    }
    __syncthreads();

    // ---- P3: scores + online softmax over this thread's 16 i's
    float den = 0.f;
    float wv[8] = {0.f,0.f,0.f,0.f,0.f,0.f,0.f,0.f};
    const float* adjB = adj2 + (size_t)b * 4096 + j;
    const float* relB = rel  + ((size_t)b * 4096 + j) * 8 + hh;
    const float inv_scale = 0.35355339059327379f;  // 1/sqrt(8)
    #pragma unroll 4
    for (int it = 0; it < 16; ++it) {
        const int i  = (q4 << 4) + it;
        const float a2 = adjB[(size_t)i * 64];
        const float rp = relB[(size_t)i * 512];
        const int kb = i * 64 + ((hh ^ (i & 7)) << 3);
        const float4 kA = *(const float4*)&shK[kb];
        const float4 kB = *(const float4*)&shK[kb + 4];
        float s;
        s = kA.x * q[0];
        s = fmaf(kA.y, q[1], s); s = fmaf(kA.z, q[2], s); s = fmaf(kA.w, q[3], s);
        s = fmaf(kB.x, q[4], s); s = fmaf(kB.y, q[5], s); s = fmaf(kB.z, q[6], s);
        s = fmaf(kB.w, q[7], s);
        s = fmaf(s * inv_scale, a2, rp);          // raw score (pre proj_e, unclipped)
        const int kidx = (i - j - 1) & 63;
        if (kidx < 16) {                          // sparse edge (i -> j), unique owner
            const int x = (j_local * 16 + kidx) * 8 + hh;
            const float pe = shPE[x];             // read proj_e once
            shPE[x] = s;                          // overwrite with sc_sp (in-place)
            s += pe;                              // softmax sees sc_sp + proj_e
        }
        s = fminf(fmaxf(s, -5.f), 5.f);
        const float ex = __expf(s);
        den += ex;
        const float4 vA = *(const float4*)&shV[kb];
        const float4 vB = *(const float4*)&shV[kb + 4];
        wv[0] = fmaf(ex, vA.x, wv[0]); wv[1] = fmaf(ex, vA.y, wv[1]);
        wv[2] = fmaf(ex, vA.z, wv[2]); wv[3] = fmaf(ex, vA.w, wv[3]);
        wv[4] = fmaf(ex, vB.x, wv[4]); wv[5] = fmaf(ex, vB.y, wv[5]);
        wv[6] = fmaf(ex, vB.z, wv[6]); wv[7] = fmaf(ex, vB.w, wv[7]);
    }
    // reduce across the 4 i-quarters (lanes differ in bits 0-1)
    den += __shfl_xor(den, 1);
    den += __shfl_xor(den, 2);
    #pragma unroll
    for (int u = 0; u < 8; ++u) {
        wv[u] += __shfl_xor(wv[u], 1);
        wv[u] += __shfl_xor(wv[u], 2);
    }
    __syncthreads();                 // all K/V reads + PE->SC swaps complete

    // ---- P4: coalesced sc_sp dump (2 threads per sparse row); wV -> dead shK
    {
        const int row = t >> 1, pp = t & 1;
        *(float4*)(scsp + (size_t)((size_t)b * 1024 + joff * 16 + row) * 8 + pp * 4) =
            *(const float4*)&shPE[row * 8 + pp * 4];
    }
    if (q4 == 0) {
        const float id = 1.f / den;
        float* wp = &shK[j_local * 64 + hh * 8];   // shK := wV[32][64], plain layout
        *(float4*)(wp)     = make_float4(wv[0]*id, wv[1]*id, wv[2]*id, wv[3]*id);
        *(float4*)(wp + 4) = make_float4(wv[4]*id, wv[5]*id, wv[6]*id, wv[7]*id);
    }
    __syncthreads();

    // ---- P5: h_out = wV @ Wo^T + bo. thread = (rl = t>>5, c2 = (t&31)*2), 2 cols
    {
        const int rl = t >> 5;
        const int c0 = (t & 31) * 2;
        float acc[2];
        acc[0] = bo[c0]; acc[1] = bo[c0 + 1];
        #pragma unroll 1
        for (int k0 = 0; k0 < 4; ++k0) {
            float tv[16];
            #pragma unroll
            for (int u = 0; u < 4; ++u) {
                const float4 x = *(const float4*)&shK[rl * 64 + k0 * 16 + u * 4];
                tv[u*4+0] = x.x; tv[u*4+1] = x.y; tv[u*4+2] = x.z; tv[u*4+3] = x.w;
            }
            #pragma unroll
            for (int u = 0; u < 2; ++u) {
                const float* wo = Wo + (c0 + u) * 64 + k0 * 16;  // uniform-ish -> s_load
                #pragma unroll
                for (int k = 0; k < 16; ++k)
                    acc[u] = fmaf(tv[k], wo[k], acc[u]);
            }
        }
        float* orow = h_out + (size_t)(b * 64 + joff + rl) * 64 + c0;
        *(float2*)orow = make_float2(acc[0], acc[1]);
    }
}

// Fold: e_out = e @ Woe^T + sc_sp @ M2^T + bc,  M2 = Woe@Wap [64x8],
// bc[c] = boe[c] + sum_k bap[k]*Woe[c,k].
__global__ void prep_kernel(const float* __restrict__ Wap, const float* __restrict__ bap,
                            const float* __restrict__ Woe, const float* __restrict__ boe,
                            float* __restrict__ M2)
{
    const int t = blockIdx.x * 64 + threadIdx.x;   // 576 threads total
    if (t < 512) {
        const int c = t >> 3, hq = t & 7;
        float s = 0.f;
        #pragma unroll 8
        for (int k = 0; k < 64; ++k) s = fmaf(Woe[c * 64 + k], Wap[k * 8 + hq], s);
        M2[t] = s;
    } else if (t < 576) {
        const int c = t - 512;
        float s = boe[c];
        #pragma unroll 8
        for (int k = 0; k < 64; ++k) s = fmaf(bap[k], Woe[c * 64 + k], s);
        M2[512 + c] = s;
    }
}

// eout: LDS-tiled, 64 rows/block, wave = 16-col group, lane = row. Full row
// hoisted to registers (one b128 burst) -> pure u-major FMA + s_load stream.
// (r9: improved -- left out of top-5. DO NOT PERTURB.)
__global__ __launch_bounds__(256, 2) void eout_kernel(
    const float* __restrict__ e,
    const float* __restrict__ scsp,
    const float* __restrict__ Woe,
    const float* __restrict__ M2g,     // [512] M2 then [64] bc
    float* __restrict__ e_out)
{
    __shared__ float shE[64 * 64];   // swizzled: chunk cc of row r at r*64 + ((cc^(r&15))<<2)
    __shared__ float shS[64 * 8];

    const int t    = threadIdx.x;
    const int base = blockIdx.x * 64;

    {   // coop e-tile load: thread = (r = t>>2, qq = t&3), 4 float4
        const int r = t >> 2, qq = t & 3;
        const float* ep = e + (size_t)(base + r) * 64 + qq * 16;
        #pragma unroll
        for (int u = 0; u < 4; ++u) {
            const float4 x = ((const float4*)ep)[u];
            const int cc = qq * 4 + u;
            *(float4*)&shE[r * 64 + ((cc ^ (r & 15)) << 2)] = x;
        }
    }
    if (t < 128) {
        const int r = t >> 1, pp = t & 1;
        *(float4*)&shS[r * 8 + pp * 4] =
            *(const float4*)(scsp + (size_t)(base + r) * 8 + pp * 4);
    }
    __syncthreads();

    const int w = __builtin_amdgcn_readfirstlane(t >> 6);  // col group, uniform
    const int r = t & 63;

    // hoist full row + sc into registers: one LDS burst, then zero DS in FMA stream
    float ev[64];
    #pragma unroll
    for (int v = 0; v < 16; ++v) {
        const float4 x = *(const float4*)&shE[r * 64 + ((v ^ (r & 15)) << 2)];
        ev[v*4+0] = x.x; ev[v*4+1] = x.y; ev[v*4+2] = x.z; ev[v*4+3] = x.w;
    }
    float sc[8];
    {
        const float4 a  = *(const float4*)&shS[r * 8];
        const float4 c4 = *(const float4*)&shS[r * 8 + 4];
        sc[0]=a.x; sc[1]=a.y; sc[2]=a.z; sc[3]=a.w;
        sc[4]=c4.x; sc[5]=c4.y; sc[6]=c4.z; sc[7]=c4.w;
    }
    float acc[16];
    #pragma unroll
    for (int u = 0; u < 16; ++u) {
        const int c = w * 16 + u;                       // wave-uniform
        float s = M2g[512 + c];
        #pragma unroll
        for (int hq = 0; hq < 8; ++hq)
            s = fmaf(sc[hq], M2g[c * 8 + hq], s);
        acc[u] = s;
    }
    #pragma unroll
    for (int u = 0; u < 16; ++u) {
        const float* wr = Woe + (w * 16 + u) * 64;      // uniform -> s_load stream
        #pragma unroll
        for (int k = 0; k < 64; ++k)
            acc[u] = fmaf(ev[k], wr[k], acc[u]);
    }
    float* orow = e_out + (size_t)(base + r) * 64 + w * 16;
    #pragma unroll
    for (int u = 0; u < 4; ++u)
        *(float4*)&orow[u * 4] =
            make_float4(acc[u*4+0], acc[u*4+1], acc[u*4+2], acc[u*4+3]);
}

extern "C" void kernel_launch(void* const* d_in, const int* in_sizes, int n_in,
                              void* d_out, int out_size, void* d_ws, size_t ws_size,
                              hipStream_t stream) {
    const float* h    = (const float*)d_in[0];
    const float* e    = (const float*)d_in[1];
    const float* adj2 = (const float*)d_in[2];
    const float* rel  = (const float*)d_in[3];
    const float* Wq   = (const float*)d_in[4];  const float* bq  = (const float*)d_in[5];
    const float* Wk   = (const float*)d_in[6];  const float* bk  = (const float*)d_in[7];
    const float* Wv   = (const float*)d_in[8];  const float* bv  = (const float*)d_in[9];
    const float* Wpe  = (const float*)d_in[10]; const float* bpe = (const float*)d_in[11];
    const float* Wap  = (const float*)d_in[12]; const float* bap = (const float*)d_in[13];
    const float* Wo   = (const float*)d_in[14]; const float* bo  = (const float*)d_in[15];
    const float* Woe  = (const float*)d_in[16]; const float* boe = (const float*)d_in[17];

    float* out  = (float*)d_out;
    float* hout = out;                        // [16384*64]
    float* eout = out + 16384 * 64;           // [262144*64], staging (dead at eout time)
    float* Qs   = eout;                       // 1048576 floats
    float* Ks   = eout + 1048576;
    float* Vs   = eout + 2097152;
    float* PEs  = eout + 3145728;             // 2097152 floats
    float* ws   = (float*)d_ws;
    float* scsp = ws;                         // [262144*8]
    float* M2g  = ws + 2097152;               // [576]

    prep_kernel<<<dim3(9), dim3(64), 0, stream>>>(Wap, bap, Woe, boe, M2g);
    qkvpe_kernel<<<dim3(768), dim3(512), 0, stream>>>(
        h, e, Wq, bq, Wk, bk, Wv, bv, Wpe, bpe, Qs, Ks, Vs, PEs);
    attn_kernel<<<dim3(512), dim3(1024), 0, stream>>>(
        Qs, Ks, Vs, PEs, adj2, rel, Wo, bo, hout, scsp);
    eout_kernel<<<dim3(4096), dim3(256), 0, stream>>>(e, scsp, Woe, M2g, eout);
}

// Round 11
// 139.294 us; speedup vs baseline: 1.0637x; 1.0433x over previous
//
#include <hip/hip_runtime.h>

// Geometry: G=256 graphs x 64 nodes, H=8 heads x D=8, IN_DIM=EDGE_DIM=64
// EF = 1048576 full edges, ES = 262144 sparse edges.
// edge f = b*4096 + i*64 + j (src=i, dst=j); sparse s = b*1024 + j*16 + k, i=(j+1+k)&63.
//
// Staging: d_out eout region: Qs @0, Ks @1048576, Vs @2097152, PEs @3145728.
//          d_ws: scsp [262144*8] @0, M2 [576] @2097152, T [73*64] @2098176.
// NOTE launch_bounds: (X, >=4) caps VGPR at 64 and SPILLS if demand>64 (r2/r3).
// NOTE small GEMM loops with SGPR-streamed weights stay fully unrolled (r5).
// NOTE r10: attn was NOT TLP-bound (19->38% occ = no change); the limiter is the
// SCATTERED adj/rel reads (8 lines/wave-load, 6-50% utilization) -> stage via LDS
// coalesced. eout's 61us @VGPR60: allocator undoes register hoists, JIT ds_reads
// inside 64-deep dependent FMA chains -> restructure k-outer w/ transposed weights
// (16 independent FMAs per k) instead of fighting the allocator.

// qkv half (blocks 0..255) + pe half (blocks 256..767), independent.
__global__ __launch_bounds__(512, 2) void qkvpe_kernel(
    const float* __restrict__ h,
    const float* __restrict__ e,
    const float* __restrict__ Wq, const float* __restrict__ bq,
    const float* __restrict__ Wk, const float* __restrict__ bk,
    const float* __restrict__ Wv, const float* __restrict__ bv,
    const float* __restrict__ Wpe, const float* __restrict__ bpe,
    float* __restrict__ Qs, float* __restrict__ Ks, float* __restrict__ Vs,
    float* __restrict__ PEs)
{
    const int t = threadIdx.x;
    if (blockIdx.x < 256) {
        const int b    = blockIdx.x;
        const int lane = t & 63;
        const int wu   = __builtin_amdgcn_readfirstlane(t >> 6);   // 8 cols per wave
        const float* hrow = h + (size_t)(b * 64 + lane) * 64;
        float accQ[8], accK[8], accV[8];
        #pragma unroll
        for (int cc = 0; cc < 8; ++cc) {
            const int c = wu * 8 + cc;
            accQ[cc] = bq[c]; accK[cc] = bk[c]; accV[cc] = bv[c];
        }
        #pragma unroll 1
        for (int k0 = 0; k0 < 4; ++k0) {
            float hv[16];
            #pragma unroll
            for (int u = 0; u < 4; ++u) {
                const float4 x = ((const float4*)hrow)[k0 * 4 + u];
                hv[u*4+0] = x.x; hv[u*4+1] = x.y; hv[u*4+2] = x.z; hv[u*4+3] = x.w;
            }
            #pragma unroll
            for (int cc = 0; cc < 8; ++cc) {
                const int c = wu * 8 + cc;
                const float* wq  = Wq + c * 64 + k0 * 16;   // wave-uniform -> s_load
                const float* wk  = Wk + c * 64 + k0 * 16;
                const float* wvp = Wv + c * 64 + k0 * 16;
                #pragma unroll
                for (int k = 0; k < 16; ++k) {
                    accQ[cc] = fmaf(hv[k], wq[k],  accQ[cc]);
                    accK[cc] = fmaf(hv[k], wk[k],  accK[cc]);
                    accV[cc] = fmaf(hv[k], wvp[k], accV[cc]);
                }
            }
        }
        const size_t o = (size_t)(b * 64 + lane) * 64 + wu * 8;
        *(float4*)(Qs + o)     = make_float4(accQ[0], accQ[1], accQ[2], accQ[3]);
        *(float4*)(Qs + o + 4) = make_float4(accQ[4], accQ[5], accQ[6], accQ[7]);
        *(float4*)(Ks + o)     = make_float4(accK[0], accK[1], accK[2], accK[3]);
        *(float4*)(Ks + o + 4) = make_float4(accK[4], accK[5], accK[6], accK[7]);
        *(float4*)(Vs + o)     = make_float4(accV[0], accV[1], accV[2], accV[3]);
        *(float4*)(Vs + o + 4) = make_float4(accV[4], accV[5], accV[6], accV[7]);
    } else {
        const int row = (blockIdx.x - 256) * 512 + t;      // 0..ES-1
        const float* erow = e + (size_t)row * 64;
        float acc[8];
        #pragma unroll
        for (int h2 = 0; h2 < 8; ++h2) acc[h2] = bpe[h2];
        #pragma unroll 1
        for (int k0 = 0; k0 < 4; ++k0) {
            float ev[16];
            #pragma unroll
            for (int u = 0; u < 4; ++u) {
                const float4 x = ((const float4*)erow)[k0 * 4 + u];
                ev[u*4+0] = x.x; ev[u*4+1] = x.y; ev[u*4+2] = x.z; ev[u*4+3] = x.w;
            }
            #pragma unroll
            for (int h2 = 0; h2 < 8; ++h2) {
                const float* wp = Wpe + h2 * 64 + k0 * 16;  // uniform -> s_load
                #pragma unroll
                for (int k = 0; k < 16; ++k)
                    acc[h2] = fmaf(ev[k], wp[k], acc[h2]);
            }
        }
        float* p0 = PEs + (size_t)row * 8;
        *(float4*)(p0)     = make_float4(acc[0], acc[1], acc[2], acc[3]);
        *(float4*)(p0 + 4) = make_float4(acc[4], acc[5], acc[6], acc[7]);
    }
}

// Core: 1024 threads = (j_local 0..31, hh 0..7, q4 0..3); thread's i's are
// i = c4*16 + it2*4 + q4 (so every thread works in every 16-i chunk).
// rel/adj staged per-chunk via COALESCED float4 loads into padded LDS.
#define STAGE_RELADJ(c4_) {                                                   \
    const int il_ = t >> 6;                                                   \
    *(float4*)&shRel[il_ * 264 + (t & 63) * 4] =                              \
        *(const float4*)(relBase + ((c4_) * 16 + il_) * 512 + (t & 63) * 4);  \
    if (t < 512) {                                                            \
        const int ia_ = t >> 5, jl_ = t & 31;                                 \
        shAdj[ia_ * 36 + jl_] = adjBase[((c4_) * 16 + ia_) * 64 + jl_];       \
    } }

__global__ __launch_bounds__(1024, 2) void attn_kernel(
    const float* __restrict__ Qs, const float* __restrict__ Ks,
    const float* __restrict__ Vs, const float* __restrict__ PEs,
    const float* __restrict__ adj2,
    const float* __restrict__ rel,
    const float* __restrict__ Wo, const float* __restrict__ bo,
    float* __restrict__ h_out,
    float* __restrict__ scsp)
{
    __shared__ float shK[64 * 64];    // swizzled: row r, colgrp g at r*64+((g^(r&7))<<3)
    __shared__ float shV[64 * 64];    // (shK reused as wV[32][64] after the loop)
    __shared__ float shPE[512 * 8];   // proj_e -> overwritten in-place with sc_sp
    __shared__ float shRel[16 * 264]; // [il][jl*8+hh], pad 8 -> conflict-free reads
    __shared__ float shAdj[16 * 36];  // [il][jl], pad 4

    const int b2   = blockIdx.x;
    const int b    = b2 >> 1;
    const int joff = (b2 & 1) << 5;          // 0 or 32
    const int t    = threadIdx.x;

    const int j_local = t >> 5;              // 0..31
    const int hh      = (t >> 2) & 7;        // 0..7
    const int q4      = t & 3;               // 0..3
    const int j       = joff + j_local;

    const float* relBase = rel  + (size_t)b * 32768 + joff * 8;  // +i*512+jl*8+hh
    const float* adjBase = adj2 + (size_t)b * 4096  + joff;      // +i*64+jl

    // ---- stage K, V (swizzled), PE, rel/adj chunk 0; Q per-thread
    {
        const int r  = t >> 4;               // 0..63
        const int gh = t & 15;
        const int g  = gh >> 1, lo = (gh & 1) * 4;
        const int d  = r * 64 + ((g ^ (r & 7)) << 3) + lo;
        const int so = r * 64 + g * 8 + lo;
        shK[d + 0] = Ks[(size_t)b * 4096 + so + 0];
        shK[d + 1] = Ks[(size_t)b * 4096 + so + 1];
        shK[d + 2] = Ks[(size_t)b * 4096 + so + 2];
        shK[d + 3] = Ks[(size_t)b * 4096 + so + 3];
        shV[d + 0] = Vs[(size_t)b * 4096 + so + 0];
        shV[d + 1] = Vs[(size_t)b * 4096 + so + 1];
        shV[d + 2] = Vs[(size_t)b * 4096 + so + 2];
        shV[d + 3] = Vs[(size_t)b * 4096 + so + 3];
        *(float4*)&shPE[t * 4] =
            *(const float4*)(PEs + ((size_t)b * 1024 + joff * 16) * 8 + t * 4);
    }
    STAGE_RELADJ(0);
    float q[8];
    {
        const float* qp = Qs + (size_t)(b * 64 + j) * 64 + hh * 8;
        const float4 a = *(const float4*)qp;
        const float4 c = *(const float4*)(qp + 4);
        q[0]=a.x; q[1]=a.y; q[2]=a.z; q[3]=a.w;
        q[4]=c.x; q[5]=c.y; q[6]=c.z; q[7]=c.w;
    }

    // ---- P3: scores + online softmax, 4 chunks x 4 i's per thread
    float den = 0.f;
    float wv[8] = {0.f,0.f,0.f,0.f,0.f,0.f,0.f,0.f};
    const float inv_scale = 0.35355339059327379f;  // 1/sqrt(8)
    #pragma unroll 1
    for (int c4 = 0; c4 < 4; ++c4) {
        __syncthreads();                     // staged chunk visible
        #pragma unroll
        for (int it2 = 0; it2 < 4; ++it2) {
            const int il = it2 * 4 + q4;     // 0..15 within chunk
            const int i  = c4 * 16 + il;
            const float a2 = shAdj[il * 36 + j_local];
            const float rp = shRel[il * 264 + j_local * 8 + hh];
            const int kb = i * 64 + ((hh ^ (i & 7)) << 3);
            const float4 kA = *(const float4*)&shK[kb];
            const float4 kB = *(const float4*)&shK[kb + 4];
            float s;
            s = kA.x * q[0];
            s = fmaf(kA.y, q[1], s); s = fmaf(kA.z, q[2], s); s = fmaf(kA.w, q[3], s);
            s = fmaf(kB.x, q[4], s); s = fmaf(kB.y, q[5], s); s = fmaf(kB.z, q[6], s);
            s = fmaf(kB.w, q[7], s);
            s = fmaf(s * inv_scale, a2, rp);      // raw score (pre proj_e, unclipped)
            const int kidx = (i - j - 1) & 63;
            if (kidx < 16) {                      // sparse edge (i -> j), unique owner
                const int x = (j_local * 16 + kidx) * 8 + hh;
                const float pe = shPE[x];         // read proj_e once
                shPE[x] = s;                      // overwrite with sc_sp (in-place)
                s += pe;                          // softmax sees sc_sp + proj_e
            }
            s = fminf(fmaxf(s, -5.f), 5.f);
            const float ex = __expf(s);
            den += ex;
            const float4 vA = *(const float4*)&shV[kb];
            const float4 vB = *(const float4*)&shV[kb + 4];
            wv[0] = fmaf(ex, vA.x, wv[0]); wv[1] = fmaf(ex, vA.y, wv[1]);
            wv[2] = fmaf(ex, vA.z, wv[2]); wv[3] = fmaf(ex, vA.w, wv[3]);
            wv[4] = fmaf(ex, vB.x, wv[4]); wv[5] = fmaf(ex, vB.y, wv[5]);
            wv[6] = fmaf(ex, vB.z, wv[6]); wv[7] = fmaf(ex, vB.w, wv[7]);
        }
        if (c4 < 3) {
            __syncthreads();                 // chunk reads done before overwrite
            STAGE_RELADJ(c4 + 1);
        }
    }
    // reduce across the 4 i-quarters (lanes differ in bits 0-1)
    den += __shfl_xor(den, 1);
    den += __shfl_xor(den, 2);
    #pragma unroll
    for (int u = 0; u < 8; ++u) {
        wv[u] += __shfl_xor(wv[u], 1);
        wv[u] += __shfl_xor(wv[u], 2);
    }
    __syncthreads();                 // all K/V reads + PE->SC swaps complete

    // ---- P4: coalesced sc_sp dump (2 threads per sparse row); wV -> dead shK
    {
        const int row = t >> 1, pp = t & 1;
        *(float4*)(scsp + (size_t)((size_t)b * 1024 + joff * 16 + row) * 8 + pp * 4) =
            *(const float4*)&shPE[row * 8 + pp * 4];
    }
    if (q4 == 0) {
        const float id = 1.f / den;
        float* wp = &shK[j_local * 64 + hh * 8];   // shK := wV[32][64], plain layout
        *(float4*)(wp)     = make_float4(wv[0]*id, wv[1]*id, wv[2]*id, wv[3]*id);
        *(float4*)(wp + 4) = make_float4(wv[4]*id, wv[5]*id, wv[6]*id, wv[7]*id);
    }
    __syncthreads();

    // ---- P5: h_out = wV @ Wo^T + bo. thread = (rl = t>>5, c0 = (t&31)*2), 2 cols
    {
        const int rl = t >> 5;
        const int c0 = (t & 31) * 2;
        float acc[2];
        acc[0] = bo[c0]; acc[1] = bo[c0 + 1];
        #pragma unroll 1
        for (int k0 = 0; k0 < 4; ++k0) {
            float tv[16];
            #pragma unroll
            for (int u = 0; u < 4; ++u) {
                const float4 x = *(const float4*)&shK[rl * 64 + k0 * 16 + u * 4];
                tv[u*4+0] = x.x; tv[u*4+1] = x.y; tv[u*4+2] = x.z; tv[u*4+3] = x.w;
            }
            #pragma unroll
            for (int u = 0; u < 2; ++u) {
                const float* wo = Wo + (c0 + u) * 64 + k0 * 16;
                #pragma unroll
                for (int k = 0; k < 16; ++k)
                    acc[u] = fmaf(tv[k], wo[k], acc[u]);
            }
        }
        float* orow = h_out + (size_t)(b * 64 + joff + rl) * 64 + c0;
        *(float2*)orow = make_float2(acc[0], acc[1]);
    }
}

// prep: M2/bc (for fallback eout) + T[73][64] = [Woe^T ; M2^T ; bc] (for eoutT).
__global__ void prep_kernel(const float* __restrict__ Wap, const float* __restrict__ bap,
                            const float* __restrict__ Woe, const float* __restrict__ boe,
                            float* __restrict__ M2, float* __restrict__ Tm, int hasT)
{
    const int tg = blockIdx.x * 64 + threadIdx.x;
    if (tg < 512) {
        const int c = tg >> 3, hq = tg & 7;
        float s = 0.f;
        #pragma unroll 8
        for (int k = 0; k < 64; ++k) s = fmaf(Woe[c * 64 + k], Wap[k * 8 + hq], s);
        M2[tg] = s;
    } else if (tg < 576) {
        const int c = tg - 512;
        float s = boe[c];
        #pragma unroll 8
        for (int k = 0; k < 64; ++k) s = fmaf(bap[k], Woe[c * 64 + k], s);
        M2[512 + c] = s;
    } else if (hasT && tg < 576 + 73 * 64) {
        const int idx = tg - 576;
        const int k = idx >> 6, c = idx & 63;
        float v;
        if (k < 64) {
            v = Woe[c * 64 + k];
        } else if (k < 72) {
            const int hq = k - 64;
            v = 0.f;
            #pragma unroll 8
            for (int kk = 0; kk < 64; ++kk)
                v = fmaf(Woe[c * 64 + kk], Wap[kk * 8 + hq], v);
        } else {
            v = boe[c];
            #pragma unroll 8
            for (int kk = 0; kk < 64; ++kk)
                v = fmaf(bap[kk], Woe[c * 64 + kk], v);
        }
        Tm[k * 64 + c] = v;
    }
}

// eoutT: k-outer. e^T in LDS (stride 67, conflict-free column reads); weights
// streamed row-linear from T via s_load_dwordx16; 16 INDEPENDENT FMAs per k.
__global__ __launch_bounds__(256, 2) void eoutT_kernel(
    const float* __restrict__ e,
    const float* __restrict__ scsp,
    const float* __restrict__ Tm,      // [73][64]: Woe^T, M2^T, bc
    float* __restrict__ e_out)
{
    __shared__ float shET[64 * 67];   // [c][r] stride 67
    __shared__ float shS[64 * 8];

    const int t    = threadIdx.x;
    const int base = blockIdx.x * 64;

    {   // coop e-tile load (coalesced) -> transposed LDS store
        const int r0 = t >> 2, qq = t & 3;
        const float* ep = e + (size_t)(base + r0) * 64 + qq * 16;
        #pragma unroll
        for (int v = 0; v < 4; ++v) {
            const float4 x = ((const float4*)ep)[v];
            const int c = qq * 16 + v * 4;
            shET[(c + 0) * 67 + r0] = x.x;
            shET[(c + 1) * 67 + r0] = x.y;
            shET[(c + 2) * 67 + r0] = x.z;
            shET[(c + 3) * 67 + r0] = x.w;
        }
    }
    if (t < 128) {
        const int r = t >> 1, pp = t & 1;
        *(float4*)&shS[r * 8 + pp * 4] =
            *(const float4*)(scsp + (size_t)(base + r) * 8 + pp * 4);
    }
    __syncthreads();

    const int w = __builtin_amdgcn_readfirstlane(t >> 6);  // col group, uniform
    const int r = t & 63;

    float sc[8];
    {
        const float4 a  = *(const float4*)&shS[r * 8];
        const float4 c4 = *(const float4*)&shS[r * 8 + 4];
        sc[0]=a.x; sc[1]=a.y; sc[2]=a.z; sc[3]=a.w;
        sc[4]=c4.x; sc[5]=c4.y; sc[6]=c4.z; sc[7]=c4.w;
    }
    float acc[16];
    {
        const float* bcw = Tm + 72 * 64 + w * 16;           // uniform -> s_load
        #pragma unroll
        for (int u = 0; u < 16; ++u) acc[u] = bcw[u];
    }
    #pragma unroll
    for (int k = 0; k < 64; ++k) {
        const float evk = shET[k * 67 + r];                 // 2 lanes/bank: free
        const float* wk = Tm + k * 64 + w * 16;             // uniform -> s_loadx16
        #pragma unroll
        for (int u = 0; u < 16; ++u)
            acc[u] = fmaf(evk, wk[u], acc[u]);              // 16 independent FMAs
    }
    #pragma unroll
    for (int hq = 0; hq < 8; ++hq) {
        const float* wk = Tm + (64 + hq) * 64 + w * 16;
        #pragma unroll
        for (int u = 0; u < 16; ++u)
            acc[u] = fmaf(sc[hq], wk[u], acc[u]);
    }
    float* orow = e_out + (size_t)(base + r) * 64 + w * 16;
    #pragma unroll
    for (int u = 0; u < 4; ++u)
        *(float4*)&orow[u * 4] =
            make_float4(acc[u*4+0], acc[u*4+1], acc[u*4+2], acc[u*4+3]);
}

// Fallback eout (r10 shape) if d_ws can't hold T.
__global__ __launch_bounds__(256, 2) void eout_kernel(
    const float* __restrict__ e,
    const float* __restrict__ scsp,
    const float* __restrict__ Woe,
    const float* __restrict__ M2g,
    float* __restrict__ e_out)
{
    __shared__ float shE[64 * 64];
    __shared__ float shS[64 * 8];
    const int t    = threadIdx.x;
    const int base = blockIdx.x * 64;
    {
        const int r = t >> 2, qq = t & 3;
        const float* ep = e + (size_t)(base + r) * 64 + qq * 16;
        #pragma unroll
        for (int u = 0; u < 4; ++u) {
            const float4 x = ((const float4*)ep)[u];
            const int cc = qq * 4 + u;
            *(float4*)&shE[r * 64 + ((cc ^ (r & 15)) << 2)] = x;
        }
    }
    if (t < 128) {
        const int r = t >> 1, pp = t & 1;
        *(float4*)&shS[r * 8 + pp * 4] =
            *(const float4*)(scsp + (size_t)(base + r) * 8 + pp * 4);
    }
    __syncthreads();
    const int w = __builtin_amdgcn_readfirstlane(t >> 6);
    const int r = t & 63;
    float sc[8];
    {
        const float4 a  = *(const float4*)&shS[r * 8];
        const float4 c4 = *(const float4*)&shS[r * 8 + 4];
        sc[0]=a.x; sc[1]=a.y; sc[2]=a.z; sc[3]=a.w;
        sc[4]=c4.x; sc[5]=c4.y; sc[6]=c4.z; sc[7]=c4.w;
    }
    float acc[16];
    #pragma unroll
    for (int u = 0; u < 16; ++u) {
        const int c = w * 16 + u;
        float s = M2g[512 + c];
        #pragma unroll
        for (int hq = 0; hq < 8; ++hq)
            s = fmaf(sc[hq], M2g[c * 8 + hq], s);
        acc[u] = s;
    }
    #pragma unroll
    for (int k0 = 0; k0 < 4; ++k0) {
        float ev[16];
        #pragma unroll
        for (int v = 0; v < 4; ++v) {
            const int cc = k0 * 4 + v;
            const float4 x = *(const float4*)&shE[r * 64 + ((cc ^ (r & 15)) << 2)];
            ev[v*4+0] = x.x; ev[v*4+1] = x.y; ev[v*4+2] = x.z; ev[v*4+3] = x.w;
        }
        #pragma unroll
        for (int u = 0; u < 16; ++u) {
            const float* wr = Woe + (w * 16 + u) * 64 + k0 * 16;
            #pragma unroll
            for (int k = 0; k < 16; ++k)
                acc[u] = fmaf(ev[k], wr[k], acc[u]);
        }
    }
    float* orow = e_out + (size_t)(base + r) * 64 + w * 16;
    #pragma unroll
    for (int u = 0; u < 4; ++u)
        *(float4*)&orow[u * 4] =
            make_float4(acc[u*4+0], acc[u*4+1], acc[u*4+2], acc[u*4+3]);
}

extern "C" void kernel_launch(void* const* d_in, const int* in_sizes, int n_in,
                              void* d_out, int out_size, void* d_ws, size_t ws_size,
                              hipStream_t stream) {
    const float* h    = (const float*)d_in[0];
    const float* e    = (const float*)d_in[1];
    const float* adj2 = (const float*)d_in[2];
    const float* rel  = (const float*)d_in[3];
    const float* Wq   = (const float*)d_in[4];  const float* bq  = (const float*)d_in[5];
    const float* Wk   = (const float*)d_in[6];  const float* bk  = (const float*)d_in[7];
    const float* Wv   = (const float*)d_in[8];  const float* bv  = (const float*)d_in[9];
    const float* Wpe  = (const float*)d_in[10]; const float* bpe = (const float*)d_in[11];
    const float* Wap  = (const float*)d_in[12]; const float* bap = (const float*)d_in[13];
    const float* Wo   = (const float*)d_in[14]; const float* bo  = (const float*)d_in[15];
    const float* Woe  = (const float*)d_in[16]; const float* boe = (const float*)d_in[17];

    float* out  = (float*)d_out;
    float* hout = out;                        // [16384*64]
    float* eout = out + 16384 * 64;           // [262144*64], staging (dead at eout time)
    float* Qs   = eout;                       // 1048576 floats
    float* Ks   = eout + 1048576;
    float* Vs   = eout + 2097152;
    float* PEs  = eout + 3145728;             // 2097152 floats
    float* ws   = (float*)d_ws;
    float* scsp = ws;                         // [262144*8]
    float* M2g  = ws + 2097152;               // [576]
    float* Tm   = ws + 2098176;               // [73*64]
    const int hasT = (ws_size >= (size_t)(2098176 + 73 * 64) * sizeof(float)) ? 1 : 0;

    prep_kernel<<<dim3(82), dim3(64), 0, stream>>>(Wap, bap, Woe, boe, M2g, Tm, hasT);
    qkvpe_kernel<<<dim3(768), dim3(512), 0, stream>>>(
        h, e, Wq, bq, Wk, bk, Wv, bv, Wpe, bpe, Qs, Ks, Vs, PEs);
    attn_kernel<<<dim3(512), dim3(1024), 0, stream>>>(
        Qs, Ks, Vs, PEs, adj2, rel, Wo, bo, hout, scsp);
    if (hasT)
        eoutT_kernel<<<dim3(4096), dim3(256), 0, stream>>>(e, scsp, Tm, eout);
    else
        eout_kernel<<<dim3(4096), dim3(256), 0, stream>>>(e, scsp, Woe, M2g, eout);
}